// Round 13
// baseline (312.026 us; speedup 1.0000x reference)
//
#include <hip/hip_runtime.h>
#include <math.h>

// Problem constants (fixed by the reference)
#define NND 50000   // nodes
#define LNP 50048   // padded rows: 782 * 64, guard-free gemm
#define NED 600000  // edges
#define CD  128     // channels (in = hid = 128)
#define NG  64      // graphs
#define NBLK 196    // ceil(NND/256) scan blocks
#define GROWS 64    // rows per fused block
#define SMAX 1152   // LDS-staged csr span cap (mean 768, sigma ~28 -> 13.9 sigma)
#define APAD 136    // abuf row stride in shorts: 272B = 68 dwords, 68%32=4 ->
                    // 16 l16-lanes spread over 8 bank groups (2-way = free)

typedef short s8v  __attribute__((ext_vector_type(8)));   // 8 bf16 (raw bits) = 4 VGPRs
typedef float f4v  __attribute__((ext_vector_type(4)));   // MFMA accumulator
typedef float f2v  __attribute__((ext_vector_type(2)));
typedef unsigned short u16x8 __attribute__((ext_vector_type(8)));

static __device__ __forceinline__ unsigned short f2bf(float f) {
  union { float f; unsigned u; } v; v.f = f;
  unsigned r = v.u + 0x7fffu + ((v.u >> 16) & 1u);   // round-to-nearest-even
  return (unsigned short)(r >> 16);
}
// truncating f32->bf16: EXACT when the value is fp8-representable (mantissa fits)
static __device__ __forceinline__ unsigned short f2bf_t(float f) {
  union { float f; unsigned u; } v; v.f = f;
  return (unsigned short)(v.u >> 16);
}
// 4 floats -> 4 packed OCP e4m3 bytes (HW RNE+sat)
static __device__ __forceinline__ unsigned f2fp8x4(float a, float b, float c, float d) {
  int r = __builtin_amdgcn_cvt_pk_fp8_f32(a, b, 0, false);
  r = __builtin_amdgcn_cvt_pk_fp8_f32(c, d, r, true);
  return (unsigned)r;
}
// 8 packed fp8 bytes -> 8 bf16 (exact: e4m3 subset of bf16)
static __device__ __forceinline__ s8v fp8x8_to_bf16(uint2 v) {
  f2v c0 = __builtin_amdgcn_cvt_pk_f32_fp8(v.x, false);
  f2v c1 = __builtin_amdgcn_cvt_pk_f32_fp8(v.x, true);
  f2v c2 = __builtin_amdgcn_cvt_pk_f32_fp8(v.y, false);
  f2v c3 = __builtin_amdgcn_cvt_pk_f32_fp8(v.y, true);
  union { u16x8 u; s8v s; } o;
  o.u[0] = f2bf_t(c0.x); o.u[1] = f2bf_t(c0.y);
  o.u[2] = f2bf_t(c1.x); o.u[3] = f2bf_t(c1.y);
  o.u[4] = f2bf_t(c2.x); o.u[5] = f2bf_t(c2.y);
  o.u[6] = f2bf_t(c3.x); o.u[7] = f2bf_t(c3.y);
  return o.s;
}
// async global->LDS, 16B per lane (m97 pattern: wave-uniform LDS base + lane*16)
static __device__ __forceinline__ void g2lds8(const unsigned char* g, unsigned char* l) {
  __builtin_amdgcn_global_load_lds(
      (const __attribute__((address_space(1))) unsigned*)g,
      (__attribute__((address_space(3))) unsigned*)l, 16, 0, 0);
}

// ---- block sums of cnt: bsum[b] = sum(cnt[b*256 .. b*256+255]) ----
__global__ __launch_bounds__(256) void bsum_k(const int* __restrict__ cnt,
                                              int* __restrict__ bsum) {
  __shared__ int s[256];
  int i = blockIdx.x * 256 + threadIdx.x;
  s[threadIdx.x] = (i < NND) ? cnt[i] : 0;
  __syncthreads();
  for (int off = 128; off > 0; off >>= 1) {
    if (threadIdx.x < off) s[threadIdx.x] += s[threadIdx.x + off];
    __syncthreads();
  }
  if (threadIdx.x == 0) bsum[blockIdx.x] = s[0];
}

// ---- merged scan: each block scans the 196 bsums (L2-hot) for its prefix,
// then its 256 cnts. Block 0 also computes gb[] and offs[NND].
__global__ __launch_bounds__(256) void escan2_k(const int* __restrict__ cnt,
                                                const int* __restrict__ bsum,
                                                int* __restrict__ offs,
                                                int* __restrict__ cur,
                                                const int* __restrict__ batch,
                                                int* __restrict__ gb) {
  __shared__ int sb[256];   // scan of block sums
  __shared__ int s[256];    // scan of this block's cnts
  const int t = threadIdx.x;
  const int bid = blockIdx.x;

  sb[t] = (t < NBLK) ? bsum[t] : 0;
  if (bid == 0 && t <= NG) {            // graph boundaries (independent work)
    int lo = 0, hi = NND;
    while (lo < hi) {
      int mid = (lo + hi) >> 1;
      if (batch[mid] < t) lo = mid + 1; else hi = mid;
    }
    gb[t] = lo;
  }
  __syncthreads();
  for (int off = 1; off < 256; off <<= 1) {   // inclusive H-S over block sums
    int v = (t >= off) ? sb[t - off] : 0;
    __syncthreads();
    sb[t] += v;
    __syncthreads();
  }
  const int boff = (bid == 0) ? 0 : sb[bid - 1];
  if (bid == 0 && t == NBLK - 1) offs[NND] = sb[t];   // grand total

  const int i = bid * 256 + t;
  const int v = (i < NND) ? cnt[i] : 0;
  s[t] = v;
  __syncthreads();
  for (int off = 1; off < 256; off <<= 1) {   // inclusive H-S over cnts
    int u = (t >= off) ? s[t - off] : 0;
    __syncthreads();
    s[t] += u;
    __syncthreads();
  }
  if (i < NND) {
    int excl = s[t] - v + boff;                // inclusive - self = exclusive
    offs[i] = excl;
    cur[i]  = excl;
  }
}

// ---- CSR fill: csr[pos] = src for edges grouped by dst ----
__global__ void fill_k(const int* __restrict__ src, const int* __restrict__ dst,
                       int* __restrict__ cur, int* __restrict__ csr) {
  int e = blockIdx.x * blockDim.x + threadIdx.x;
  if (e >= NED) return;
  int d = dst[e];
  int pos = atomicAdd(&cur[d], 1);
  csr[pos] = src[e];
}

// ---- merged preamble: x->fp8 (range 0), weight transposes (range 1),
//      degree count for CSR (range 2, atomics hidden under streaming) ----
struct WPtrs { const float* w[8]; unsigned short* wt[8]; };
__global__ void prep_k(const float* __restrict__ x, unsigned* __restrict__ x8,
                       WPtrs p, const int* __restrict__ dst, int* __restrict__ cnt) {
  int t = blockIdx.x * blockDim.x + threadIdx.x;
  if (t < NND * 32) {                 // one float4 chunk per thread
    float4 v = reinterpret_cast<const float4*>(x)[t];
    x8[t] = f2fp8x4(v.x, v.y, v.z, v.w);
  } else {
    int u = t - NND * 32;             // 8*16384 weight elements
    if (u < 8 * CD * CD) {
      int m = u >> 14, r = u & (CD * CD - 1);
      int n = r >> 7, k = r & 127;
      p.wt[m][r] = f2bf(p.w[m][k * CD + n]);
    } else {
      int e = u - 8 * CD * CD;        // NED degree counts
      if (e < NED) atomicAdd(&cnt[dst[e]], 1);
    }
  }
}

// ---- FUSED SAGE layer — PHASE-DOUBLING ABLATION round.
// The 43us/dispatch floor is ~9x my cycle model; removal-ablation breaks
// correctness, so phases are DOUBLED instead (identical inputs -> identical
// results; asm memory clobber between passes blocks dead-store-elim / CSE):
//   V0: R12-exact (reference within this compile)
//   V1: gather loop x2 — marginal = cache-hot, queue-free gather issue cost
//   V2: MFMA+store phase x2 — marginal = LDS-read+MFMA+store issue cost
// Layer->variant: L0=V0, L1=V1, L2=V2, L3=V0(pooled). Within-probe deltas
// only (rule #19: co-compiled variants perturb absolutes).
template<int V>
__global__ __launch_bounds__(256, 4) void sage_k(
    const unsigned* __restrict__ xq,
    const int* __restrict__ csr, const int* __restrict__ offs,
    const unsigned short* __restrict__ WlT, const unsigned short* __restrict__ WrT,
    const float* __restrict__ bias, unsigned char* __restrict__ h8,
    const int* __restrict__ batch, float* __restrict__ pooled) {
  __shared__ unsigned short abuf[GROWS * APAD]; // 17.4 KB aggregated means (bf16)
  __shared__ unsigned char  x8buf[GROWS * CD];  // 8 KB root features (fp8 DMA)
  __shared__ int sB[GROWS];                     // graph ids of the block's rows
  __shared__ int scsr[SMAX];                    // 4.5 KB staged csr indices

  const int tid  = threadIdx.x;
  const int wave = tid >> 6;
  const int lane = tid & 63;
  const int quad = lane >> 4;
  const int l16  = lane & 15;
  const size_t rbase = (size_t)blockIdx.x * GROWS;

  // stage the block's contiguous csr span into LDS (one coalesced nt burst)
  const int eb0  = offs[rbase];
  const int span = offs[(rbase + GROWS < NND) ? rbase + GROWS : NND] - eb0;
  const bool big = span > SMAX;                 // block-uniform fallback
  if (!big) {
    for (int k = tid; k < span; k += 256)
      scsr[k] = __builtin_nontemporal_load(&csr[eb0 + k]);
  }

  // batch ids for pooling (tiny)
  if (pooled && tid < GROWS) {
    size_t row = rbase + tid;
    sB[tid] = (row < NND) ? batch[row] : -1;
  }

  __syncthreads();   // scsr ready (before DMA issue: keeps DMA<->gather overlap)

  // root fp8 DMA (fire-and-forget): 512 slots of 16B; SOURCE chunk pre-swizzled
  // so LDS slot s holds global chunk (s&7)^(row&7) of its row
  {
    const unsigned char* xg = (const unsigned char*)xq;
#pragma unroll
    for (int j = 0; j < 2; ++j) {
      const int s = j * 256 + tid;            // row = s/8, LDS 16B slot = s%8
      const int row = s >> 3;
      const int c = (s & 7) ^ (row & 7);      // swizzled source chunk
      g2lds8(xg + (rbase + row) * CD + c * 16, &x8buf[(size_t)s * 16]);
    }
  }

  // B fragments -> registers (overlaps DMA; weights are L2-hot)
  s8v bL[2][4], bR[2][4];
#pragma unroll
  for (int nt = 0; nt < 2; ++nt) {
    const int n = wave * 32 + nt * 16 + l16;
#pragma unroll
    for (int kk = 0; kk < 4; ++kk) {
      size_t woff = (size_t)n * CD + kk * 32 + quad * 8;
      bL[nt][kk] = *reinterpret_cast<const s8v*>(WlT + woff);
      bR[nt][kk] = *reinterpret_cast<const s8v*>(WrT + woff);
    }
  }
  const float bv0 = bias[wave * 32 + l16];
  const float bv1 = bias[wave * 32 + 16 + l16];

  // Gather phase: 32 teams x 8 lanes; team handles rows rbase + team*2 + i
  {
    const int team = tid >> 3;
    const int tl   = tid & 7;                  // owns channels [tl*16, tl*16+16)
    const unsigned* base = xq + tl * 4;        // 4 u32 = 16 fp8 channels
    auto run = [&](auto fetch) {
      for (int i = 0; i < 2; ++i) {
        const int rl = team * 2 + i;
        const size_t row = rbase + rl;
        u16x8 o0 = {}, o1 = {};
        if (row < NND) {
          const int e0 = offs[row], e1 = offs[row + 1];
          f2v a[8] = {};
          int e = e0;
          for (; e + 4 <= e1; e += 4) {
            int s[4];
#pragma unroll
            for (int j = 0; j < 4; ++j) s[j] = fetch(e + j);
            uint4 v[4];
#pragma unroll
            for (int j = 0; j < 4; ++j)
              v[j] = *reinterpret_cast<const uint4*>(base + (size_t)s[j] * 32);
#pragma unroll
            for (int j = 0; j < 4; ++j) {
              a[0] += __builtin_amdgcn_cvt_pk_f32_fp8(v[j].x, false);
              a[1] += __builtin_amdgcn_cvt_pk_f32_fp8(v[j].x, true);
              a[2] += __builtin_amdgcn_cvt_pk_f32_fp8(v[j].y, false);
              a[3] += __builtin_amdgcn_cvt_pk_f32_fp8(v[j].y, true);
              a[4] += __builtin_amdgcn_cvt_pk_f32_fp8(v[j].z, false);
              a[5] += __builtin_amdgcn_cvt_pk_f32_fp8(v[j].z, true);
              a[6] += __builtin_amdgcn_cvt_pk_f32_fp8(v[j].w, false);
              a[7] += __builtin_amdgcn_cvt_pk_f32_fp8(v[j].w, true);
            }
          }
          for (; e < e1; ++e) {
            uint4 v = *reinterpret_cast<const uint4*>(base + (size_t)fetch(e) * 32);
            a[0] += __builtin_amdgcn_cvt_pk_f32_fp8(v.x, false);
            a[1] += __builtin_amdgcn_cvt_pk_f32_fp8(v.x, true);
            a[2] += __builtin_amdgcn_cvt_pk_f32_fp8(v.y, false);
            a[3] += __builtin_amdgcn_cvt_pk_f32_fp8(v.y, true);
            a[4] += __builtin_amdgcn_cvt_pk_f32_fp8(v.z, false);
            a[5] += __builtin_amdgcn_cvt_pk_f32_fp8(v.z, true);
            a[6] += __builtin_amdgcn_cvt_pk_f32_fp8(v.w, false);
            a[7] += __builtin_amdgcn_cvt_pk_f32_fp8(v.w, true);
          }
          const float invd = 1.0f / fmaxf((float)(e1 - e0), 1.0f);
#pragma unroll
          for (int c = 0; c < 4; ++c) {
            o0[2 * c]     = f2bf(a[c].x * invd);
            o0[2 * c + 1] = f2bf(a[c].y * invd);
            o1[2 * c]     = f2bf(a[4 + c].x * invd);
            o1[2 * c + 1] = f2bf(a[4 + c].y * invd);
          }
        }
        *reinterpret_cast<u16x8*>(abuf + rl * APAD + tl * 16)     = o0;
        *reinterpret_cast<u16x8*>(abuf + rl * APAD + tl * 16 + 8) = o1;
      }
    };
    auto run_all = [&]() {
      if (!big) run([&](int e) { return scsr[e - eb0]; });
      else      run([&](int e) { return csr[e]; });
    };
    if constexpr (V == 1) {
      run_all();                       // extra pass (cache-hot on re-run)
      asm volatile("" ::: "memory");   // block dead-store-elim of pass 1
    }
    run_all();
  }

  __syncthreads();   // drains DMA (vmcnt) + LDS writes + barrier

  const bool fast = pooled && (rbase + GROWS <= NND) && (sB[0] == sB[GROWS - 1]);
  const int c0 = wave * 32 + l16;
  float p0 = 0.f, p1 = 0.f;

  // MFMA phase (abuf padded stride; x8buf XOR'd chunk index). V2: doubled.
  const int nrep = (V == 2 && !pooled) ? 2 : 1;
#pragma unroll 1
  for (int rep = 0; rep < nrep; ++rep) {
    if (rep) asm volatile("" ::: "memory");   // force re-read + recompute
#pragma unroll
    for (int rt = 0; rt < GROWS / 16; ++rt) {
      const int rowl = rt * 16 + l16;
      const int sw   = rowl & 7;
      const unsigned short* arow = abuf + rowl * APAD + quad * 8;
      const unsigned char*  xrow = x8buf + rowl * CD;
      f4v acc0 = {}, acc1 = {};
#pragma unroll
      for (int kk = 0; kk < 4; ++kk) {
        s8v aA = *reinterpret_cast<const s8v*>(arow + kk * 32);   // ds_read_b128
        uint2 xv = *reinterpret_cast<const uint2*>(
            xrow + ((((quad >> 1) + kk * 2) ^ sw) << 4) + ((quad & 1) << 3));
        s8v aX = fp8x8_to_bf16(xv);
        acc0 = __builtin_amdgcn_mfma_f32_16x16x32_bf16(aA, bL[0][kk], acc0, 0, 0, 0);
        acc0 = __builtin_amdgcn_mfma_f32_16x16x32_bf16(aX, bR[0][kk], acc0, 0, 0, 0);
        acc1 = __builtin_amdgcn_mfma_f32_16x16x32_bf16(aA, bL[1][kk], acc1, 0, 0, 0);
        acc1 = __builtin_amdgcn_mfma_f32_16x16x32_bf16(aX, bR[1][kk], acc1, 0, 0, 0);
      }
      const size_t row0 = rbase + rt * 16 + quad * 4;
#pragma unroll
      for (int r = 0; r < 4; ++r) {
        const size_t row = row0 + r;
        float v0 = fmaxf(acc0[r] + bv0, 0.0f);
        float v1 = fmaxf(acc1[r] + bv1, 0.0f);
        if (h8) {
          int q0 = __builtin_amdgcn_cvt_pk_fp8_f32(v0, v0, 0, false);
          int q1 = __builtin_amdgcn_cvt_pk_fp8_f32(v1, v1, 0, false);
          // nt: h8 consumed by a LATER dispatch — idempotent under V2 rep
          __builtin_nontemporal_store((unsigned char)q0, h8 + row * CD + c0);
          __builtin_nontemporal_store((unsigned char)q1, h8 + row * CD + c0 + 16);
        }
        if (pooled) {   // nrep==1 whenever pooled != nullptr (no double-count)
          if (fast) {
            p0 += v0; p1 += v1;
          } else {
            int g = sB[rt * 16 + quad * 4 + r];
            if (g >= 0) {
              atomicAdd(&pooled[g * CD + c0], v0);
              atomicAdd(&pooled[g * CD + c0 + 16], v1);
            }
          }
        }
      }
    }
  }

  if (fast) {   // butterfly column-reduce across quads, one atomic pair per col
    p0 += __shfl_xor(p0, 16, 64);
    p0 += __shfl_xor(p0, 32, 64);
    p1 += __shfl_xor(p1, 16, 64);
    p1 += __shfl_xor(p1, 32, 64);
    if (quad == 0) {
      const int g = sB[0];
      atomicAdd(&pooled[g * CD + c0], p0);
      atomicAdd(&pooled[g * CD + c0 + 16], p1);
    }
  }
}

// ---- classifier: out[g] = sigmoid(dot(pooled[g]/cnt, Wc) + bc) ----
// SEPARATE kernel by design (R11: fusing it into sage_k costs 2.4x on ALL
// layers via compile-level schedule perturbation).
__global__ void final_k(const float* __restrict__ pooled, const int* __restrict__ gb,
                        const float* __restrict__ Wc, const float* __restrict__ bc,
                        float* __restrict__ out) {
  int g = blockIdx.x;
  int lane = threadIdx.x;
  float part = pooled[g * CD + lane] * Wc[lane] +
               pooled[g * CD + 64 + lane] * Wc[64 + lane];
#pragma unroll
  for (int off = 32; off > 0; off >>= 1) part += __shfl_down(part, off, 64);
  if (lane == 0) {
    float cnt = (float)(gb[g + 1] - gb[g]);
    float z = part / fmaxf(cnt, 1.0f) + bc[0];
    out[g] = 1.0f / (1.0f + expf(-z));
  }
}

extern "C" void kernel_launch(void* const* d_in, const int* in_sizes, int n_in,
                              void* d_out, int out_size, void* d_ws, size_t ws_size,
                              hipStream_t stream) {
  const float* x   = (const float*)d_in[0];
  const int*   ei  = (const int*)d_in[1];
  const int*   src = ei;             // edge_index[0]
  const int*   dst = ei + NED;       // edge_index[1]
  // d_in[2] = edge_weight: unused by the reference
  const int*   batch = (const int*)d_in[3];
  const float* Wc = (const float*)d_in[16];
  const float* bc = (const float*)d_in[17];
  float* out = (float*)d_out;

  char* w = (char*)d_ws;
  auto alloc = [&](size_t bytes) {
    char* p = w; w += (bytes + 255) & ~(size_t)255; return p;
  };
  // cnti + pooled first and contiguous: one memset covers both
  int* cnti = (int*)alloc(NND * 4);
  float* pooled = (float*)alloc(NG * CD * 4);
  size_t zspan = (size_t)(w - (char*)cnti);
  int* offs = (int*)alloc((NND + 1) * 4);
  int* cur  = (int*)alloc(NND * 4);
  int* csr  = (int*)alloc((size_t)NED * 4);
  int* gb   = (int*)alloc((NG + 1) * 4);
  int* bsum = (int*)alloc(256 * 4);
  unsigned char* x8a = (unsigned char*)alloc((size_t)LNP * CD);
  unsigned char* x8b = (unsigned char*)alloc((size_t)LNP * CD);
  WPtrs wp;
  for (int i = 0; i < 4; ++i) {
    wp.w[2 * i]     = (const float*)d_in[4 + 3 * i];      // Wl{i+1}
    wp.w[2 * i + 1] = (const float*)d_in[5 + 3 * i];      // Wr{i+1}
  }
  for (int i = 0; i < 8; ++i) wp.wt[i] = (unsigned short*)alloc(CD * CD * 2);
  const float* bs[4] = {(const float*)d_in[6],  (const float*)d_in[9],
                        (const float*)d_in[12], (const float*)d_in[15]};

  hipMemsetAsync(cnti, 0, zspan, stream);

  // preamble: fp8 convert + weight transposes + degree count in ONE kernel
  prep_k<<<(NND * 32 + 8 * CD * CD + NED + 255) / 256, 256, 0, stream>>>(
      x, (unsigned*)x8a, wp, dst, cnti);

  // CSR build: 2-kernel scan, then fill
  bsum_k<<<NBLK, 256, 0, stream>>>(cnti, bsum);
  escan2_k<<<NBLK, 256, 0, stream>>>(cnti, bsum, offs, cur, batch, gb);
  fill_k<<<(NED + 255) / 256, 256, 0, stream>>>(src, dst, cur, csr);

  const int ggrid = LNP / GROWS;   // 782, guard-free
  // Ablation layout: L0=V0 (ref), L1=V1 (2x gather), L2=V2 (2x MFMA+store),
  // L3=V0+pooled. All outputs bit-identical to R12.
  sage_k<0><<<ggrid, 256, 0, stream>>>((const unsigned*)x8a, csr, offs,
                                       wp.wt[0], wp.wt[1], bs[0],
                                       x8b, batch, nullptr);
  sage_k<1><<<ggrid, 256, 0, stream>>>((const unsigned*)x8b, csr, offs,
                                       wp.wt[2], wp.wt[3], bs[1],
                                       x8a, batch, nullptr);
  sage_k<2><<<ggrid, 256, 0, stream>>>((const unsigned*)x8a, csr, offs,
                                       wp.wt[4], wp.wt[5], bs[2],
                                       x8b, batch, nullptr);
  sage_k<0><<<ggrid, 256, 0, stream>>>((const unsigned*)x8b, csr, offs,
                                       wp.wt[6], wp.wt[7], bs[3],
                                       nullptr, batch, pooled);

  final_k<<<NG, 64, 0, stream>>>(pooled, gb, Wc, bc, out);
}

// Round 14
// 311.937 us; speedup vs baseline: 1.0003x; 1.0003x over previous
//
#include <hip/hip_runtime.h>
#include <math.h>

// Problem constants (fixed by the reference)
#define NND 50000   // nodes
#define LNP 50048   // padded rows: 782 * 64, guard-free gemm
#define NED 600000  // edges
#define CD  128     // channels (in = hid = 128)
#define NG  64      // graphs
#define NBLK 196    // ceil(NND/256) scan blocks
#define GROWS 64    // rows per fused block
#define SMAX 1152   // LDS-staged csr span cap (mean 768, sigma ~28 -> 13.9 sigma)
#define APAD 136    // abuf row stride in shorts: 272B = 68 dwords, 68%32=4 ->
                    // 16 l16-lanes spread over 8 bank groups (2-way = free)

typedef short s8v  __attribute__((ext_vector_type(8)));   // 8 bf16 (raw bits) = 4 VGPRs
typedef float f4v  __attribute__((ext_vector_type(4)));   // MFMA accumulator
typedef float f2v  __attribute__((ext_vector_type(2)));
typedef unsigned short u16x8 __attribute__((ext_vector_type(8)));

static __device__ __forceinline__ unsigned short f2bf(float f) {
  union { float f; unsigned u; } v; v.f = f;
  unsigned r = v.u + 0x7fffu + ((v.u >> 16) & 1u);   // round-to-nearest-even
  return (unsigned short)(r >> 16);
}
// truncating f32->bf16: EXACT when the value is fp8-representable (mantissa fits)
static __device__ __forceinline__ unsigned short f2bf_t(float f) {
  union { float f; unsigned u; } v; v.f = f;
  return (unsigned short)(v.u >> 16);
}
// 4 floats -> 4 packed OCP e4m3 bytes (HW RNE+sat)
static __device__ __forceinline__ unsigned f2fp8x4(float a, float b, float c, float d) {
  int r = __builtin_amdgcn_cvt_pk_fp8_f32(a, b, 0, false);
  r = __builtin_amdgcn_cvt_pk_fp8_f32(c, d, r, true);
  return (unsigned)r;
}
// 8 packed fp8 bytes -> 8 bf16 (exact: e4m3 subset of bf16)
static __device__ __forceinline__ s8v fp8x8_to_bf16(uint2 v) {
  f2v c0 = __builtin_amdgcn_cvt_pk_f32_fp8(v.x, false);
  f2v c1 = __builtin_amdgcn_cvt_pk_f32_fp8(v.x, true);
  f2v c2 = __builtin_amdgcn_cvt_pk_f32_fp8(v.y, false);
  f2v c3 = __builtin_amdgcn_cvt_pk_f32_fp8(v.y, true);
  union { u16x8 u; s8v s; } o;
  o.u[0] = f2bf_t(c0.x); o.u[1] = f2bf_t(c0.y);
  o.u[2] = f2bf_t(c1.x); o.u[3] = f2bf_t(c1.y);
  o.u[4] = f2bf_t(c2.x); o.u[5] = f2bf_t(c2.y);
  o.u[6] = f2bf_t(c3.x); o.u[7] = f2bf_t(c3.y);
  return o.s;
}
// async global->LDS, 16B per lane (m97 pattern: wave-uniform LDS base + lane*16)
static __device__ __forceinline__ void g2lds8(const unsigned char* g, unsigned char* l) {
  __builtin_amdgcn_global_load_lds(
      (const __attribute__((address_space(1))) unsigned*)g,
      (__attribute__((address_space(3))) unsigned*)l, 16, 0, 0);
}

// ---- block sums of cnt: bsum[b] = sum(cnt[b*256 .. b*256+255]) ----
__global__ __launch_bounds__(256) void bsum_k(const int* __restrict__ cnt,
                                              int* __restrict__ bsum) {
  __shared__ int s[256];
  int i = blockIdx.x * 256 + threadIdx.x;
  s[threadIdx.x] = (i < NND) ? cnt[i] : 0;
  __syncthreads();
  for (int off = 128; off > 0; off >>= 1) {
    if (threadIdx.x < off) s[threadIdx.x] += s[threadIdx.x + off];
    __syncthreads();
  }
  if (threadIdx.x == 0) bsum[blockIdx.x] = s[0];
}

// ---- merged scan: each block scans the 196 bsums (L2-hot) for its prefix,
// then its 256 cnts. Block 0 also computes gb[] and offs[NND].
__global__ __launch_bounds__(256) void escan2_k(const int* __restrict__ cnt,
                                                const int* __restrict__ bsum,
                                                int* __restrict__ offs,
                                                int* __restrict__ cur,
                                                const int* __restrict__ batch,
                                                int* __restrict__ gb) {
  __shared__ int sb[256];   // scan of block sums
  __shared__ int s[256];    // scan of this block's cnts
  const int t = threadIdx.x;
  const int bid = blockIdx.x;

  sb[t] = (t < NBLK) ? bsum[t] : 0;
  if (bid == 0 && t <= NG) {            // graph boundaries (independent work)
    int lo = 0, hi = NND;
    while (lo < hi) {
      int mid = (lo + hi) >> 1;
      if (batch[mid] < t) lo = mid + 1; else hi = mid;
    }
    gb[t] = lo;
  }
  __syncthreads();
  for (int off = 1; off < 256; off <<= 1) {   // inclusive H-S over block sums
    int v = (t >= off) ? sb[t - off] : 0;
    __syncthreads();
    sb[t] += v;
    __syncthreads();
  }
  const int boff = (bid == 0) ? 0 : sb[bid - 1];
  if (bid == 0 && t == NBLK - 1) offs[NND] = sb[t];   // grand total

  const int i = bid * 256 + t;
  const int v = (i < NND) ? cnt[i] : 0;
  s[t] = v;
  __syncthreads();
  for (int off = 1; off < 256; off <<= 1) {   // inclusive H-S over cnts
    int u = (t >= off) ? s[t - off] : 0;
    __syncthreads();
    s[t] += u;
    __syncthreads();
  }
  if (i < NND) {
    int excl = s[t] - v + boff;                // inclusive - self = exclusive
    offs[i] = excl;
    cur[i]  = excl;
  }
}

// ---- CSR fill: csr[pos] = src for edges grouped by dst ----
__global__ void fill_k(const int* __restrict__ src, const int* __restrict__ dst,
                       int* __restrict__ cur, int* __restrict__ csr) {
  int e = blockIdx.x * blockDim.x + threadIdx.x;
  if (e >= NED) return;
  int d = dst[e];
  int pos = atomicAdd(&cur[d], 1);
  csr[pos] = src[e];
}

// ---- merged preamble: x->fp8 SPLIT tables (range 0), weight transposes
//      (range 1), degree count (range 2). R14: feature tables are stored as
//      two 3.2 MB half-tables (channels 0-63 | 64-127), each 64 B/row, so a
//      channel-half gather pass has a working set < 4 MB/XCD L2.
struct WPtrs { const float* w[8]; unsigned short* wt[8]; };
__global__ void prep_k(const float* __restrict__ x, unsigned* __restrict__ x8,
                       WPtrs p, const int* __restrict__ dst, int* __restrict__ cnt) {
  int t = blockIdx.x * blockDim.x + threadIdx.x;
  if (t < NND * 32) {                 // one float4 chunk (4 channels) per thread
    float4 v = reinterpret_cast<const float4*>(x)[t];
    unsigned q = f2fp8x4(v.x, v.y, v.z, v.w);
    int node = t >> 5, c4 = t & 31;   // channels [4*c4, 4*c4+4)
    unsigned* dstp = (c4 < 16) ? x8 + node * 16 + c4                    // lo half
                               : x8 + LNP * 16 + node * 16 + (c4 - 16); // hi half
    *dstp = q;
  } else {
    int u = t - NND * 32;             // 8*16384 weight elements
    if (u < 8 * CD * CD) {
      int m = u >> 14, r = u & (CD * CD - 1);
      int n = r >> 7, k = r & 127;
      p.wt[m][r] = f2bf(p.w[m][k * CD + n]);
    } else {
      int e = u - 8 * CD * CD;        // NED degree counts
      if (e < NED) atomicAdd(&cnt[dst[e]], 1);
    }
  }
}

// ---- FUSED SAGE layer v10 = R12 + CHANNEL-SPLIT two-pass gather.
// R13 doubling-ablation: hot gather re-run and doubled MFMA are ~free ->
// the 43us floor is memory-side service of cold misses: 76.8 MB/layer of
// random 128B reads from a 6.4 MB table (> 4MB/XCD L2) at 1.79 TB/s eff.
// Fix: tables stored as two 3.2 MB halves; gather runs TWO passes, each
// touching only one half -> per-pass working set L2-RESIDENT. All 782
// blocks are co-resident, so pass phases align chip-wide. Same total
// bytes; loop-doubling issue cost measured ~free (R13 V1). Per-channel
// accumulation order unchanged -> bit-identical output. abuf/x8buf/MFMA
// layouts unchanged. Classifier stays in final_k (R11: fusing it = 2.4x).
__global__ __launch_bounds__(256, 4) void sage_k(
    const unsigned* __restrict__ xq,
    const int* __restrict__ csr, const int* __restrict__ offs,
    const unsigned short* __restrict__ WlT, const unsigned short* __restrict__ WrT,
    const float* __restrict__ bias, unsigned char* __restrict__ h8,
    const int* __restrict__ batch, float* __restrict__ pooled) {
  __shared__ unsigned short abuf[GROWS * APAD]; // 17.4 KB aggregated means (bf16)
  __shared__ unsigned char  x8buf[GROWS * CD];  // 8 KB root features (fp8 DMA)
  __shared__ int sB[GROWS];                     // graph ids of the block's rows
  __shared__ int scsr[SMAX];                    // 4.5 KB staged csr indices

  const int tid  = threadIdx.x;
  const int wave = tid >> 6;
  const int lane = tid & 63;
  const int quad = lane >> 4;
  const int l16  = lane & 15;
  const size_t rbase = (size_t)blockIdx.x * GROWS;
  const unsigned char* xlo = (const unsigned char*)xq;
  const unsigned char* xhi = xlo + (size_t)LNP * 64;

  // stage the block's contiguous csr span into LDS (one coalesced nt burst)
  const int eb0  = offs[rbase];
  const int span = offs[(rbase + GROWS < NND) ? rbase + GROWS : NND] - eb0;
  const bool big = span > SMAX;                 // block-uniform fallback
  if (!big) {
    for (int k = tid; k < span; k += 256)
      scsr[k] = __builtin_nontemporal_load(&csr[eb0 + k]);
  }

  // batch ids for pooling (tiny)
  if (pooled && tid < GROWS) {
    size_t row = rbase + tid;
    sB[tid] = (row < NND) ? batch[row] : -1;
  }

  __syncthreads();   // scsr ready (before DMA issue: keeps DMA<->gather overlap)

  // root fp8 DMA (fire-and-forget): 512 slots of 16B; SOURCE chunk pre-swizzled
  // so LDS slot s holds logical chunk (s&7)^(row&7); chunks 0-3 from lo half,
  // 4-7 from hi half (x8buf layout identical to R12)
  {
#pragma unroll
    for (int j = 0; j < 2; ++j) {
      const int s = j * 256 + tid;            // row = s/8, LDS 16B slot = s%8
      const int row = s >> 3;
      const int c = (s & 7) ^ (row & 7);      // swizzled logical chunk
      const unsigned char* srcp = (c < 4)
          ? xlo + (rbase + row) * 64 + c * 16
          : xhi + (rbase + row) * 64 + (c - 4) * 16;
      g2lds8(srcp, &x8buf[(size_t)s * 16]);
    }
  }

  // B fragments -> registers (overlaps DMA; weights are L2-hot)
  s8v bL[2][4], bR[2][4];
#pragma unroll
  for (int nt = 0; nt < 2; ++nt) {
    const int n = wave * 32 + nt * 16 + l16;
#pragma unroll
    for (int kk = 0; kk < 4; ++kk) {
      size_t woff = (size_t)n * CD + kk * 32 + quad * 8;
      bL[nt][kk] = *reinterpret_cast<const s8v*>(WlT + woff);
      bR[nt][kk] = *reinterpret_cast<const s8v*>(WrT + woff);
    }
  }
  const float bv0 = bias[wave * 32 + l16];
  const float bv1 = bias[wave * 32 + 16 + l16];

  // Gather phase: 32 teams x 8 lanes; TWO channel-half passes.
  // Pass p: lane tl owns channels [p*64 + tl*8, +8) = one uint2 (8B) per edge;
  // team's 8 lanes coalesce to one 64B request per edge within half-table p.
  {
    const int team = tid >> 3;
    const int tl   = tid & 7;
    auto run = [&](auto fetch) {
#pragma unroll 1
      for (int p = 0; p < 2; ++p) {
        const unsigned char* base = (p ? xhi : xlo) + tl * 8;
        for (int i = 0; i < 2; ++i) {
          const int rl = team * 2 + i;
          const size_t row = rbase + rl;
          u16x8 o = {};
          if (row < NND) {
            const int e0 = offs[row], e1 = offs[row + 1];
            f2v a[4] = {};
            int e = e0;
            for (; e + 4 <= e1; e += 4) {
              int s[4];
#pragma unroll
              for (int j = 0; j < 4; ++j) s[j] = fetch(e + j);
              uint2 v[4];
#pragma unroll
              for (int j = 0; j < 4; ++j)
                v[j] = *reinterpret_cast<const uint2*>(base + (size_t)s[j] * 64);
#pragma unroll
              for (int j = 0; j < 4; ++j) {
                a[0] += __builtin_amdgcn_cvt_pk_f32_fp8(v[j].x, false);
                a[1] += __builtin_amdgcn_cvt_pk_f32_fp8(v[j].x, true);
                a[2] += __builtin_amdgcn_cvt_pk_f32_fp8(v[j].y, false);
                a[3] += __builtin_amdgcn_cvt_pk_f32_fp8(v[j].y, true);
              }
            }
            for (; e < e1; ++e) {
              uint2 v = *reinterpret_cast<const uint2*>(base + (size_t)fetch(e) * 64);
              a[0] += __builtin_amdgcn_cvt_pk_f32_fp8(v.x, false);
              a[1] += __builtin_amdgcn_cvt_pk_f32_fp8(v.x, true);
              a[2] += __builtin_amdgcn_cvt_pk_f32_fp8(v.y, false);
              a[3] += __builtin_amdgcn_cvt_pk_f32_fp8(v.y, true);
            }
            const float invd = 1.0f / fmaxf((float)(e1 - e0), 1.0f);
#pragma unroll
            for (int c = 0; c < 4; ++c) {
              o[2 * c]     = f2bf(a[c].x * invd);
              o[2 * c + 1] = f2bf(a[c].y * invd);
            }
          }
          // abuf[row][channel] layout unchanged vs R12
          *reinterpret_cast<u16x8*>(abuf + rl * APAD + p * 64 + tl * 8) = o;
        }
      }
    };
    if (!big) run([&](int e) { return scsr[e - eb0]; });
    else      run([&](int e) { return csr[e]; });
  }

  __syncthreads();   // drains DMA (vmcnt) + LDS writes + barrier

  const bool fast = pooled && (rbase + GROWS <= NND) && (sB[0] == sB[GROWS - 1]);
  const int c0 = wave * 32 + l16;
  float p0 = 0.f, p1 = 0.f;

  // MFMA phase (abuf padded stride; x8buf XOR'd chunk index) — unchanged
#pragma unroll
  for (int rt = 0; rt < GROWS / 16; ++rt) {
    const int rowl = rt * 16 + l16;
    const int sw   = rowl & 7;
    const unsigned short* arow = abuf + rowl * APAD + quad * 8;
    const unsigned char*  xrow = x8buf + rowl * CD;
    f4v acc0 = {}, acc1 = {};
#pragma unroll
    for (int kk = 0; kk < 4; ++kk) {
      s8v aA = *reinterpret_cast<const s8v*>(arow + kk * 32);   // ds_read_b128
      uint2 xv = *reinterpret_cast<const uint2*>(
          xrow + ((((quad >> 1) + kk * 2) ^ sw) << 4) + ((quad & 1) << 3));
      s8v aX = fp8x8_to_bf16(xv);
      acc0 = __builtin_amdgcn_mfma_f32_16x16x32_bf16(aA, bL[0][kk], acc0, 0, 0, 0);
      acc0 = __builtin_amdgcn_mfma_f32_16x16x32_bf16(aX, bR[0][kk], acc0, 0, 0, 0);
      acc1 = __builtin_amdgcn_mfma_f32_16x16x32_bf16(aA, bL[1][kk], acc1, 0, 0, 0);
      acc1 = __builtin_amdgcn_mfma_f32_16x16x32_bf16(aX, bR[1][kk], acc1, 0, 0, 0);
    }
    const size_t row0 = rbase + rt * 16 + quad * 4;
#pragma unroll
    for (int r = 0; r < 4; ++r) {
      const size_t row = row0 + r;
      float v0 = fmaxf(acc0[r] + bv0, 0.0f);
      float v1 = fmaxf(acc1[r] + bv1, 0.0f);
      if (h8) {
        int q0 = __builtin_amdgcn_cvt_pk_fp8_f32(v0, v0, 0, false);
        int q1 = __builtin_amdgcn_cvt_pk_fp8_f32(v1, v1, 0, false);
        // split-layout next-layer table; channels c0, c0+16 stay in one half
        unsigned char* hdst = (wave < 2)
            ? h8 + row * 64 + c0
            : h8 + (size_t)LNP * 64 + row * 64 + (c0 - 64);
        // nt: consumed by a LATER dispatch — don't pollute L2 now
        __builtin_nontemporal_store((unsigned char)q0, hdst);
        __builtin_nontemporal_store((unsigned char)q1, hdst + 16);
      }
      if (pooled) {
        if (fast) {
          p0 += v0; p1 += v1;
        } else {
          int g = sB[rt * 16 + quad * 4 + r];
          if (g >= 0) {
            atomicAdd(&pooled[g * CD + c0], v0);
            atomicAdd(&pooled[g * CD + c0 + 16], v1);
          }
        }
      }
    }
  }

  if (fast) {   // butterfly column-reduce across quads, one atomic pair per col
    p0 += __shfl_xor(p0, 16, 64);
    p0 += __shfl_xor(p0, 32, 64);
    p1 += __shfl_xor(p1, 16, 64);
    p1 += __shfl_xor(p1, 32, 64);
    if (quad == 0) {
      const int g = sB[0];
      atomicAdd(&pooled[g * CD + c0], p0);
      atomicAdd(&pooled[g * CD + c0 + 16], p1);
    }
  }
}

// ---- classifier: out[g] = sigmoid(dot(pooled[g]/cnt, Wc) + bc) ----
// SEPARATE kernel by design (R11: fusing it into sage_k costs 2.4x on ALL
// layers via compile-level schedule perturbation).
__global__ void final_k(const float* __restrict__ pooled, const int* __restrict__ gb,
                        const float* __restrict__ Wc, const float* __restrict__ bc,
                        float* __restrict__ out) {
  int g = blockIdx.x;
  int lane = threadIdx.x;
  float part = pooled[g * CD + lane] * Wc[lane] +
               pooled[g * CD + 64 + lane] * Wc[64 + lane];
#pragma unroll
  for (int off = 32; off > 0; off >>= 1) part += __shfl_down(part, off, 64);
  if (lane == 0) {
    float cnt = (float)(gb[g + 1] - gb[g]);
    float z = part / fmaxf(cnt, 1.0f) + bc[0];
    out[g] = 1.0f / (1.0f + expf(-z));
  }
}

extern "C" void kernel_launch(void* const* d_in, const int* in_sizes, int n_in,
                              void* d_out, int out_size, void* d_ws, size_t ws_size,
                              hipStream_t stream) {
  const float* x   = (const float*)d_in[0];
  const int*   ei  = (const int*)d_in[1];
  const int*   src = ei;             // edge_index[0]
  const int*   dst = ei + NED;       // edge_index[1]
  // d_in[2] = edge_weight: unused by the reference
  const int*   batch = (const int*)d_in[3];
  const float* Wc = (const float*)d_in[16];
  const float* bc = (const float*)d_in[17];
  float* out = (float*)d_out;

  char* w = (char*)d_ws;
  auto alloc = [&](size_t bytes) {
    char* p = w; w += (bytes + 255) & ~(size_t)255; return p;
  };
  // cnti + pooled first and contiguous: one memset covers both
  int* cnti = (int*)alloc(NND * 4);
  float* pooled = (float*)alloc(NG * CD * 4);
  size_t zspan = (size_t)(w - (char*)cnti);
  int* offs = (int*)alloc((NND + 1) * 4);
  int* cur  = (int*)alloc(NND * 4);
  int* csr  = (int*)alloc((size_t)NED * 4);
  int* gb   = (int*)alloc((NG + 1) * 4);
  int* bsum = (int*)alloc(256 * 4);
  // split feature tables: [lo: LNP*64 B][hi: LNP*64 B] per buffer
  unsigned char* x8a = (unsigned char*)alloc((size_t)LNP * CD);
  unsigned char* x8b = (unsigned char*)alloc((size_t)LNP * CD);
  WPtrs wp;
  for (int i = 0; i < 4; ++i) {
    wp.w[2 * i]     = (const float*)d_in[4 + 3 * i];      // Wl{i+1}
    wp.w[2 * i + 1] = (const float*)d_in[5 + 3 * i];      // Wr{i+1}
  }
  for (int i = 0; i < 8; ++i) wp.wt[i] = (unsigned short*)alloc(CD * CD * 2);
  const float* bs[4] = {(const float*)d_in[6],  (const float*)d_in[9],
                        (const float*)d_in[12], (const float*)d_in[15]};

  hipMemsetAsync(cnti, 0, zspan, stream);

  // preamble: fp8 convert (split layout) + weight transposes + degree count
  prep_k<<<(NND * 32 + 8 * CD * CD + NED + 255) / 256, 256, 0, stream>>>(
      x, (unsigned*)x8a, wp, dst, cnti);

  // CSR build: 2-kernel scan, then fill
  bsum_k<<<NBLK, 256, 0, stream>>>(cnti, bsum);
  escan2_k<<<NBLK, 256, 0, stream>>>(cnti, bsum, offs, cur, batch, gb);
  fill_k<<<(NED + 255) / 256, 256, 0, stream>>>(src, dst, cur, csr);

  unsigned char* qcur = x8a;
  unsigned char* qnxt = x8b;
  const int ggrid = LNP / GROWS;   // 782, guard-free
  for (int l = 0; l < 4; ++l) {
    if (l < 3) {
      sage_k<<<ggrid, 256, 0, stream>>>((const unsigned*)qcur, csr, offs,
                                        wp.wt[2 * l], wp.wt[2 * l + 1], bs[l],
                                        qnxt, batch, nullptr);
      unsigned char* q = qcur; qcur = qnxt; qnxt = q;
    } else {
      // last layer: no feature output — pooling fused into epilogue
      sage_k<<<ggrid, 256, 0, stream>>>((const unsigned*)qcur, csr, offs,
                                        wp.wt[2 * l], wp.wt[2 * l + 1], bs[l],
                                        nullptr, batch, pooled);
    }
  }

  final_k<<<NG, 64, 0, stream>>>(pooled, gb, Wc, bc, out);
}

// Round 15
// 289.367 us; speedup vs baseline: 1.0783x; 1.0780x over previous
//
#include <hip/hip_runtime.h>
#include <math.h>

// Problem constants (fixed by the reference)
#define NND 50000   // nodes
#define LNP 50048   // padded rows: 782 * 64, guard-free gemm
#define NED 600000  // edges
#define CD  128     // channels (in = hid = 128)
#define NG  64      // graphs
#define NBLK 196    // ceil(NND/256) scan blocks
#define GROWS 64    // rows per fused block
#define SMAX 1152   // LDS-staged csr span cap (mean 768, sigma ~28 -> 13.9 sigma)
#define APAD 136    // abuf row stride in shorts: 272B = 68 dwords, 68%32=4 ->
                    // 16 l16-lanes spread over 8 bank groups (2-way = free);
                    // 272 = 17*16 keeps every ds_read_b128 16B-aligned

typedef short s8v  __attribute__((ext_vector_type(8)));   // 8 bf16 (raw bits) = 4 VGPRs
typedef float f4v  __attribute__((ext_vector_type(4)));   // MFMA accumulator
typedef float f2v  __attribute__((ext_vector_type(2)));
typedef unsigned short u16x4 __attribute__((ext_vector_type(4)));
typedef unsigned short u16x8 __attribute__((ext_vector_type(8)));

static __device__ __forceinline__ unsigned short f2bf(float f) {
  union { float f; unsigned u; } v; v.f = f;
  unsigned r = v.u + 0x7fffu + ((v.u >> 16) & 1u);   // round-to-nearest-even
  return (unsigned short)(r >> 16);
}
// truncating f32->bf16: EXACT when the value is fp8-representable (mantissa fits)
static __device__ __forceinline__ unsigned short f2bf_t(float f) {
  union { float f; unsigned u; } v; v.f = f;
  return (unsigned short)(v.u >> 16);
}
// 4 floats -> 4 packed OCP e4m3 bytes (HW RNE+sat)
static __device__ __forceinline__ unsigned f2fp8x4(float a, float b, float c, float d) {
  int r = __builtin_amdgcn_cvt_pk_fp8_f32(a, b, 0, false);
  r = __builtin_amdgcn_cvt_pk_fp8_f32(c, d, r, true);
  return (unsigned)r;
}
// 8 packed fp8 bytes -> 8 bf16 (exact: e4m3 subset of bf16)
static __device__ __forceinline__ s8v fp8x8_to_bf16(uint2 v) {
  f2v c0 = __builtin_amdgcn_cvt_pk_f32_fp8(v.x, false);
  f2v c1 = __builtin_amdgcn_cvt_pk_f32_fp8(v.x, true);
  f2v c2 = __builtin_amdgcn_cvt_pk_f32_fp8(v.y, false);
  f2v c3 = __builtin_amdgcn_cvt_pk_f32_fp8(v.y, true);
  union { u16x8 u; s8v s; } o;
  o.u[0] = f2bf_t(c0.x); o.u[1] = f2bf_t(c0.y);
  o.u[2] = f2bf_t(c1.x); o.u[3] = f2bf_t(c1.y);
  o.u[4] = f2bf_t(c2.x); o.u[5] = f2bf_t(c2.y);
  o.u[6] = f2bf_t(c3.x); o.u[7] = f2bf_t(c3.y);
  return o.s;
}
// async global->LDS, 16B per lane (m97 pattern: wave-uniform LDS base + lane*16)
static __device__ __forceinline__ void g2lds8(const unsigned char* g, unsigned char* l) {
  __builtin_amdgcn_global_load_lds(
      (const __attribute__((address_space(1))) unsigned*)g,
      (__attribute__((address_space(3))) unsigned*)l, 16, 0, 0);
}

// ---- block sums of cnt: bsum[b] = sum(cnt[b*256 .. b*256+255]) ----
__global__ __launch_bounds__(256) void bsum_k(const int* __restrict__ cnt,
                                              int* __restrict__ bsum) {
  __shared__ int s[256];
  int i = blockIdx.x * 256 + threadIdx.x;
  s[threadIdx.x] = (i < NND) ? cnt[i] : 0;
  __syncthreads();
  for (int off = 128; off > 0; off >>= 1) {
    if (threadIdx.x < off) s[threadIdx.x] += s[threadIdx.x + off];
    __syncthreads();
  }
  if (threadIdx.x == 0) bsum[blockIdx.x] = s[0];
}

// ---- merged scan: each block scans the 196 bsums (L2-hot) for its prefix,
// then its 256 cnts. Block 0 also computes gb[] and offs[NND].
__global__ __launch_bounds__(256) void escan2_k(const int* __restrict__ cnt,
                                                const int* __restrict__ bsum,
                                                int* __restrict__ offs,
                                                int* __restrict__ cur,
                                                const int* __restrict__ batch,
                                                int* __restrict__ gb) {
  __shared__ int sb[256];   // scan of block sums
  __shared__ int s[256];    // scan of this block's cnts
  const int t = threadIdx.x;
  const int bid = blockIdx.x;

  sb[t] = (t < NBLK) ? bsum[t] : 0;
  if (bid == 0 && t <= NG) {            // graph boundaries (independent work)
    int lo = 0, hi = NND;
    while (lo < hi) {
      int mid = (lo + hi) >> 1;
      if (batch[mid] < t) lo = mid + 1; else hi = mid;
    }
    gb[t] = lo;
  }
  __syncthreads();
  for (int off = 1; off < 256; off <<= 1) {   // inclusive H-S over block sums
    int v = (t >= off) ? sb[t - off] : 0;
    __syncthreads();
    sb[t] += v;
    __syncthreads();
  }
  const int boff = (bid == 0) ? 0 : sb[bid - 1];
  if (bid == 0 && t == NBLK - 1) offs[NND] = sb[t];   // grand total

  const int i = bid * 256 + t;
  const int v = (i < NND) ? cnt[i] : 0;
  s[t] = v;
  __syncthreads();
  for (int off = 1; off < 256; off <<= 1) {   // inclusive H-S over cnts
    int u = (t >= off) ? s[t - off] : 0;
    __syncthreads();
    s[t] += u;
    __syncthreads();
  }
  if (i < NND) {
    int excl = s[t] - v + boff;                // inclusive - self = exclusive
    offs[i] = excl;
    cur[i]  = excl;
  }
}

// ---- CSR fill: csr[pos] = src for edges grouped by dst ----
__global__ void fill_k(const int* __restrict__ src, const int* __restrict__ dst,
                       int* __restrict__ cur, int* __restrict__ csr) {
  int e = blockIdx.x * blockDim.x + threadIdx.x;
  if (e >= NED) return;
  int d = dst[e];
  int pos = atomicAdd(&cur[d], 1);
  csr[pos] = src[e];
}

// ---- merged preamble: x->fp8 (range 0), weight transposes (range 1),
//      degree count for CSR (range 2, atomics hidden under streaming) ----
struct WPtrs { const float* w[8]; unsigned short* wt[8]; };
__global__ void prep_k(const float* __restrict__ x, unsigned* __restrict__ x8,
                       WPtrs p, const int* __restrict__ dst, int* __restrict__ cnt) {
  int t = blockIdx.x * blockDim.x + threadIdx.x;
  if (t < NND * 32) {                 // one float4 chunk per thread
    float4 v = reinterpret_cast<const float4*>(x)[t];
    x8[t] = f2fp8x4(v.x, v.y, v.z, v.w);
  } else {
    int u = t - NND * 32;             // 8*16384 weight elements
    if (u < 8 * CD * CD) {
      int m = u >> 14, r = u & (CD * CD - 1);
      int n = r >> 7, k = r & 127;
      p.wt[m][r] = f2bf(p.w[m][k * CD + n]);
    } else {
      int e = u - 8 * CD * CD;        // NED degree counts
      if (e < NED) atomicAdd(&cnt[dst[e]], 1);
    }
  }
}

// ---- FUSED SAGE layer — R12-EXACT (measured session optimum, 289.6 us).
// R14 post-mortem closed the last open mechanism: the gather floor is
// TRANSACTION-RATE-bound (channel-split halved request size, doubled request
// count -> +4us/dispatch), so one 128B request per edge is optimal. Fixes
// carried: abuf padded stride (R9), x8buf source-swizzled DMA + XOR read
// (R10), nt stream-once traffic (R8), csr LDS staging (R6). Classifier
// SEPARATE (R11: fusing costs 2.4x on all layers).
__global__ __launch_bounds__(256, 4) void sage_k(
    const unsigned* __restrict__ xq,
    const int* __restrict__ csr, const int* __restrict__ offs,
    const unsigned short* __restrict__ WlT, const unsigned short* __restrict__ WrT,
    const float* __restrict__ bias, unsigned char* __restrict__ h8,
    const int* __restrict__ batch, float* __restrict__ pooled) {
  __shared__ unsigned short abuf[GROWS * APAD]; // 17.4 KB aggregated means (bf16)
  __shared__ unsigned char  x8buf[GROWS * CD];  // 8 KB root features (fp8 DMA)
  __shared__ int sB[GROWS];                     // graph ids of the block's rows
  __shared__ int scsr[SMAX];                    // 4.5 KB staged csr indices

  const int tid  = threadIdx.x;
  const int wave = tid >> 6;
  const int lane = tid & 63;
  const int quad = lane >> 4;
  const int l16  = lane & 15;
  const size_t rbase = (size_t)blockIdx.x * GROWS;

  // stage the block's contiguous csr span into LDS (one coalesced nt burst)
  const int eb0  = offs[rbase];
  const int span = offs[(rbase + GROWS < NND) ? rbase + GROWS : NND] - eb0;
  const bool big = span > SMAX;                 // block-uniform fallback
  if (!big) {
    for (int k = tid; k < span; k += 256)
      scsr[k] = __builtin_nontemporal_load(&csr[eb0 + k]);
  }

  // batch ids for pooling (tiny)
  if (pooled && tid < GROWS) {
    size_t row = rbase + tid;
    sB[tid] = (row < NND) ? batch[row] : -1;
  }

  __syncthreads();   // scsr ready (before DMA issue: keeps DMA<->gather overlap)

  // root fp8 DMA (fire-and-forget): 512 slots of 16B; SOURCE chunk pre-swizzled
  // so LDS slot s holds global chunk (s&7)^(row&7) of its row
  {
    const unsigned char* xg = (const unsigned char*)xq;
#pragma unroll
    for (int j = 0; j < 2; ++j) {
      const int s = j * 256 + tid;            // row = s/8, LDS 16B slot = s%8
      const int row = s >> 3;
      const int c = (s & 7) ^ (row & 7);      // swizzled source chunk
      g2lds8(xg + (rbase + row) * CD + c * 16, &x8buf[(size_t)s * 16]);
    }
  }

  // B fragments -> registers (overlaps DMA; weights are L2-hot)
  s8v bL[2][4], bR[2][4];
#pragma unroll
  for (int nt = 0; nt < 2; ++nt) {
    const int n = wave * 32 + nt * 16 + l16;
#pragma unroll
    for (int kk = 0; kk < 4; ++kk) {
      size_t woff = (size_t)n * CD + kk * 32 + quad * 8;
      bL[nt][kk] = *reinterpret_cast<const s8v*>(WlT + woff);
      bR[nt][kk] = *reinterpret_cast<const s8v*>(WrT + woff);
    }
  }
  const float bv0 = bias[wave * 32 + l16];
  const float bv1 = bias[wave * 32 + 16 + l16];

  // Gather phase: 32 teams x 8 lanes; team handles rows rbase + team*2 + i
  {
    const int team = tid >> 3;
    const int tl   = tid & 7;                  // owns channels [tl*16, tl*16+16)
    const unsigned* base = xq + tl * 4;        // 4 u32 = 16 fp8 channels
    auto run = [&](auto fetch) {
      for (int i = 0; i < 2; ++i) {
        const int rl = team * 2 + i;
        const size_t row = rbase + rl;
        u16x8 o0 = {}, o1 = {};
        if (row < NND) {
          const int e0 = offs[row], e1 = offs[row + 1];
          f2v a[8] = {};
          int e = e0;
          for (; e + 4 <= e1; e += 4) {
            int s[4];
#pragma unroll
            for (int j = 0; j < 4; ++j) s[j] = fetch(e + j);
            uint4 v[4];
#pragma unroll
            for (int j = 0; j < 4; ++j)
              v[j] = *reinterpret_cast<const uint4*>(base + (size_t)s[j] * 32);
#pragma unroll
            for (int j = 0; j < 4; ++j) {
              a[0] += __builtin_amdgcn_cvt_pk_f32_fp8(v[j].x, false);
              a[1] += __builtin_amdgcn_cvt_pk_f32_fp8(v[j].x, true);
              a[2] += __builtin_amdgcn_cvt_pk_f32_fp8(v[j].y, false);
              a[3] += __builtin_amdgcn_cvt_pk_f32_fp8(v[j].y, true);
              a[4] += __builtin_amdgcn_cvt_pk_f32_fp8(v[j].z, false);
              a[5] += __builtin_amdgcn_cvt_pk_f32_fp8(v[j].z, true);
              a[6] += __builtin_amdgcn_cvt_pk_f32_fp8(v[j].w, false);
              a[7] += __builtin_amdgcn_cvt_pk_f32_fp8(v[j].w, true);
            }
          }
          for (; e < e1; ++e) {
            uint4 v = *reinterpret_cast<const uint4*>(base + (size_t)fetch(e) * 32);
            a[0] += __builtin_amdgcn_cvt_pk_f32_fp8(v.x, false);
            a[1] += __builtin_amdgcn_cvt_pk_f32_fp8(v.x, true);
            a[2] += __builtin_amdgcn_cvt_pk_f32_fp8(v.y, false);
            a[3] += __builtin_amdgcn_cvt_pk_f32_fp8(v.y, true);
            a[4] += __builtin_amdgcn_cvt_pk_f32_fp8(v.z, false);
            a[5] += __builtin_amdgcn_cvt_pk_f32_fp8(v.z, true);
            a[6] += __builtin_amdgcn_cvt_pk_f32_fp8(v.w, false);
            a[7] += __builtin_amdgcn_cvt_pk_f32_fp8(v.w, true);
          }
          const float invd = 1.0f / fmaxf((float)(e1 - e0), 1.0f);
#pragma unroll
          for (int c = 0; c < 4; ++c) {
            o0[2 * c]     = f2bf(a[c].x * invd);
            o0[2 * c + 1] = f2bf(a[c].y * invd);
            o1[2 * c]     = f2bf(a[4 + c].x * invd);
            o1[2 * c + 1] = f2bf(a[4 + c].y * invd);
          }
        }
        *reinterpret_cast<u16x8*>(abuf + rl * APAD + tl * 16)     = o0;
        *reinterpret_cast<u16x8*>(abuf + rl * APAD + tl * 16 + 8) = o1;
      }
    };
    if (!big) run([&](int e) { return scsr[e - eb0]; });
    else      run([&](int e) { return csr[e]; });
  }

  __syncthreads();   // drains DMA (vmcnt) + LDS writes + barrier

  const bool fast = pooled && (rbase + GROWS <= NND) && (sB[0] == sB[GROWS - 1]);
  const int c0 = wave * 32 + l16;
  float p0 = 0.f, p1 = 0.f;

  // MFMA phase (abuf via padded stride; x8buf via matching XOR on chunk index)
#pragma unroll
  for (int rt = 0; rt < GROWS / 16; ++rt) {
    const int rowl = rt * 16 + l16;
    const int sw   = rowl & 7;
    const unsigned short* arow = abuf + rowl * APAD + quad * 8;
    const unsigned char*  xrow = x8buf + rowl * CD;
    f4v acc0 = {}, acc1 = {};
#pragma unroll
    for (int kk = 0; kk < 4; ++kk) {
      s8v aA = *reinterpret_cast<const s8v*>(arow + kk * 32);   // ds_read_b128
      // chunk (2kk + quad/2) of this row lives at slot (2kk + quad/2)^sw
      uint2 xv = *reinterpret_cast<const uint2*>(
          xrow + ((((quad >> 1) + kk * 2) ^ sw) << 4) + ((quad & 1) << 3));
      s8v aX = fp8x8_to_bf16(xv);
      acc0 = __builtin_amdgcn_mfma_f32_16x16x32_bf16(aA, bL[0][kk], acc0, 0, 0, 0);
      acc0 = __builtin_amdgcn_mfma_f32_16x16x32_bf16(aX, bR[0][kk], acc0, 0, 0, 0);
      acc1 = __builtin_amdgcn_mfma_f32_16x16x32_bf16(aA, bL[1][kk], acc1, 0, 0, 0);
      acc1 = __builtin_amdgcn_mfma_f32_16x16x32_bf16(aX, bR[1][kk], acc1, 0, 0, 0);
    }
    const size_t row0 = rbase + rt * 16 + quad * 4;
#pragma unroll
    for (int r = 0; r < 4; ++r) {
      const size_t row = row0 + r;
      float v0 = fmaxf(acc0[r] + bv0, 0.0f);
      float v1 = fmaxf(acc1[r] + bv1, 0.0f);
      if (h8) {
        int q0 = __builtin_amdgcn_cvt_pk_fp8_f32(v0, v0, 0, false);
        int q1 = __builtin_amdgcn_cvt_pk_fp8_f32(v1, v1, 0, false);
        // nt: h8 is consumed by a LATER dispatch — don't pollute L2 now
        __builtin_nontemporal_store((unsigned char)q0, h8 + row * CD + c0);
        __builtin_nontemporal_store((unsigned char)q1, h8 + row * CD + c0 + 16);
      }
      if (pooled) {
        if (fast) {
          p0 += v0; p1 += v1;
        } else {
          int g = sB[rt * 16 + quad * 4 + r];
          if (g >= 0) {
            atomicAdd(&pooled[g * CD + c0], v0);
            atomicAdd(&pooled[g * CD + c0 + 16], v1);
          }
        }
      }
    }
  }

  if (fast) {   // butterfly column-reduce across quads, one atomic pair per col
    p0 += __shfl_xor(p0, 16, 64);
    p0 += __shfl_xor(p0, 32, 64);
    p1 += __shfl_xor(p1, 16, 64);
    p1 += __shfl_xor(p1, 32, 64);
    if (quad == 0) {
      const int g = sB[0];
      atomicAdd(&pooled[g * CD + c0], p0);
      atomicAdd(&pooled[g * CD + c0 + 16], p1);
    }
  }
}

// ---- classifier: out[g] = sigmoid(dot(pooled[g]/cnt, Wc) + bc) ----
// SEPARATE kernel by design (R11: fusing it into sage_k costs 2.4x on ALL
// layers via compile-level schedule perturbation).
__global__ void final_k(const float* __restrict__ pooled, const int* __restrict__ gb,
                        const float* __restrict__ Wc, const float* __restrict__ bc,
                        float* __restrict__ out) {
  int g = blockIdx.x;
  int lane = threadIdx.x;
  float part = pooled[g * CD + lane] * Wc[lane] +
               pooled[g * CD + 64 + lane] * Wc[64 + lane];
#pragma unroll
  for (int off = 32; off > 0; off >>= 1) part += __shfl_down(part, off, 64);
  if (lane == 0) {
    float cnt = (float)(gb[g + 1] - gb[g]);
    float z = part / fmaxf(cnt, 1.0f) + bc[0];
    out[g] = 1.0f / (1.0f + expf(-z));
  }
}

extern "C" void kernel_launch(void* const* d_in, const int* in_sizes, int n_in,
                              void* d_out, int out_size, void* d_ws, size_t ws_size,
                              hipStream_t stream) {
  const float* x   = (const float*)d_in[0];
  const int*   ei  = (const int*)d_in[1];
  const int*   src = ei;             // edge_index[0]
  const int*   dst = ei + NED;       // edge_index[1]
  // d_in[2] = edge_weight: unused by the reference
  const int*   batch = (const int*)d_in[3];
  const float* Wc = (const float*)d_in[16];
  const float* bc = (const float*)d_in[17];
  float* out = (float*)d_out;

  char* w = (char*)d_ws;
  auto alloc = [&](size_t bytes) {
    char* p = w; w += (bytes + 255) & ~(size_t)255; return p;
  };
  // cnti + pooled first and contiguous: one memset covers both
  int* cnti = (int*)alloc(NND * 4);
  float* pooled = (float*)alloc(NG * CD * 4);
  size_t zspan = (size_t)(w - (char*)cnti);
  int* offs = (int*)alloc((NND + 1) * 4);
  int* cur  = (int*)alloc(NND * 4);
  int* csr  = (int*)alloc((size_t)NED * 4);
  int* gb   = (int*)alloc((NG + 1) * 4);
  int* bsum = (int*)alloc(256 * 4);
  unsigned char* x8a = (unsigned char*)alloc((size_t)LNP * CD);
  unsigned char* x8b = (unsigned char*)alloc((size_t)LNP * CD);
  WPtrs wp;
  for (int i = 0; i < 4; ++i) {
    wp.w[2 * i]     = (const float*)d_in[4 + 3 * i];      // Wl{i+1}
    wp.w[2 * i + 1] = (const float*)d_in[5 + 3 * i];      // Wr{i+1}
  }
  for (int i = 0; i < 8; ++i) wp.wt[i] = (unsigned short*)alloc(CD * CD * 2);
  const float* bs[4] = {(const float*)d_in[6],  (const float*)d_in[9],
                        (const float*)d_in[12], (const float*)d_in[15]};

  hipMemsetAsync(cnti, 0, zspan, stream);

  // preamble: fp8 convert + weight transposes + degree count in ONE kernel
  prep_k<<<(NND * 32 + 8 * CD * CD + NED + 255) / 256, 256, 0, stream>>>(
      x, (unsigned*)x8a, wp, dst, cnti);

  // CSR build: 2-kernel scan (bscan folded into escan2), then fill
  bsum_k<<<NBLK, 256, 0, stream>>>(cnti, bsum);
  escan2_k<<<NBLK, 256, 0, stream>>>(cnti, bsum, offs, cur, batch, gb);
  fill_k<<<(NED + 255) / 256, 256, 0, stream>>>(src, dst, cur, csr);

  unsigned char* qcur = x8a;
  unsigned char* qnxt = x8b;
  const int ggrid = LNP / GROWS;   // 782, guard-free
  for (int l = 0; l < 4; ++l) {
    if (l < 3) {
      sage_k<<<ggrid, 256, 0, stream>>>((const unsigned*)qcur, csr, offs,
                                        wp.wt[2 * l], wp.wt[2 * l + 1], bs[l],
                                        qnxt, batch, nullptr);
      unsigned char* q = qcur; qcur = qnxt; qnxt = q;
    } else {
      // last layer: no feature output — pooling fused into epilogue
      sage_k<<<ggrid, 256, 0, stream>>>((const unsigned*)qcur, csr, offs,
                                        wp.wt[2 * l], wp.wt[2 * l + 1], bs[l],
                                        nullptr, batch, pooled);
    }
  }

  final_k<<<NG, 64, 0, stream>>>(pooled, gb, Wc, bc, out);
}